// Round 5
// baseline (316.034 us; speedup 1.0000x reference)
//
#include <hip/hip_runtime.h>
#include <stdint.h>

#define B 8
#define NQ 100000
#define NCLS 10
#define NELEM 1000000        // elements per batch (NQ*NCLS)
#define NV4 250000           // float4 per batch
#define KTOP 100
#define NPTS 20
#define CAP 1024             // max candidates kept per batch (Poisson(159) >1024: ~0)
#define THREADS 256
#define CBLOCKS 128          // collect blocks per batch
#define REG 64               // candidate slots per block region (exp ~1.25 cands/block)
#define T0 3.6f              // prefilter: count>3.6 ~ Poisson(159); P(<100)~1e-6; fallback exact

// Order-preserving monotone key for f32 (larger float <-> larger key)
__device__ __forceinline__ uint32_t fkey(float x) {
  uint32_t u = __float_as_uint(x);
  return (u & 0x80000000u) ? ~u : (u | 0x80000000u);
}

__device__ __forceinline__ uint64_t composite(float logit, uint32_t idx) {
  float s = 1.0f / (1.0f + expf(-logit));
  // sorts desc by sigmoid f32 bits, then asc by index (matches top_k tie rule)
  return ((uint64_t)__float_as_uint(s) << 32) | (uint64_t)(0xFFFFFFFFu - idx);
}

// Fused: per-block collect + last-block-per-batch finalize.
__global__ void fused_kernel(const float* __restrict__ cls,
                             const float* __restrict__ bbox,
                             const float* __restrict__ pts,
                             uint32_t* __restrict__ counts,   // [B*CBLOCKS]
                             uint64_t* __restrict__ cand,     // [B*CBLOCKS][REG]
                             uint32_t* __restrict__ done,     // [B], pre-zeroed
                             float* __restrict__ out) {
  __shared__ uint64_t s[CAP];
  __shared__ uint32_t sc[CBLOCKS];
  __shared__ uint32_t red[THREADS];
  __shared__ uint32_t lcnt, s_old, s_bad, s_cnt;

  int b   = blockIdx.x / CBLOCKS;
  int sub = blockIdx.x % CBLOCKS;
  int tid = threadIdx.x;

  // ---------- phase 1: collect this block's slice ----------
  if (tid == 0) lcnt = 0;
  __syncthreads();
  {
    const float4* src = (const float4*)(cls + (size_t)b * NELEM);
    const int STRIDE = CBLOCKS * THREADS;          // 32768 float4s
    int base = sub * THREADS + tid;
    float4 v[8];
    int   idx[8];
#pragma unroll
    for (int k = 0; k < 8; ++k) {
      idx[k] = base + k * STRIDE;
      v[k] = (idx[k] < NV4) ? src[idx[k]] : make_float4(-100.f, -100.f, -100.f, -100.f);
    }
    uint64_t* region = cand + (size_t)(b * CBLOCKS + sub) * REG;
#pragma unroll
    for (int k = 0; k < 8; ++k) {
      float xs[4] = {v[k].x, v[k].y, v[k].z, v[k].w};
#pragma unroll
      for (int l = 0; l < 4; ++l) {
        if (xs[l] > T0) {
          uint32_t slot = atomicAdd(&lcnt, 1u);    // LDS atomic, ~1-2 hits/block
          if (slot < REG)
            region[slot] = composite(xs[l], (uint32_t)(4 * idx[k] + l));
        }
      }
    }
  }
  __syncthreads();
  if (tid == 0) counts[b * CBLOCKS + sub] = lcnt;  // raw (>REG -> fallback)

  // ---------- handoff: last block of this batch finalizes ----------
  __threadfence();                                  // release region/count writes
  if (tid == 0) s_old = atomicAdd(&done[b], 1u);
  __syncthreads();
  if (s_old != CBLOCKS - 1) return;
  __threadfence();                                  // acquire other blocks' writes

  // ---------- phase 2: finalize batch b ----------
  if (tid == 0) s_bad = 0;
  __syncthreads();

  uint32_t myc = 0;
  if (tid < CBLOCKS) {
    myc = counts[b * CBLOCKS + tid];
    if (myc > REG) { s_bad = 1; myc = REG; }
    sc[tid] = myc;
  }
  // Hillis-Steele inclusive scan over CBLOCKS entries
  for (int step = 1; step < CBLOCKS; step <<= 1) {
    __syncthreads();
    uint32_t add = (tid < CBLOCKS && tid >= step) ? sc[tid - step] : 0;
    __syncthreads();
    if (tid < CBLOCKS) sc[tid] += add;
  }
  __syncthreads();
  uint32_t total = sc[CBLOCKS - 1];
  uint32_t bad = s_bad || (total < KTOP) || (total > CAP);
  __syncthreads();

  uint32_t cnt;
  if (!bad) {
    // one region per thread (~1.25 elems each), latency-overlapped
    if (tid < CBLOCKS) {
      uint32_t off = sc[tid] - myc;
      const uint64_t* region = cand + (size_t)(b * CBLOCKS + tid) * REG;
      for (uint32_t j = 0; j < myc; ++j) s[off + j] = region[j];
    }
    cnt = total;
  } else {
    // exact fallback: binary-search the KTOP threshold over the raw logits.
    const float* src = cls + (size_t)b * NELEM;
    uint32_t lo = 0, hi = 0xFFFFFFFFu;
    while (lo < hi) {
      uint32_t mid = lo + ((hi - lo + 1) >> 1);
      uint32_t c = 0;
      for (int i = tid; i < NELEM; i += THREADS)
        c += (fkey(src[i]) >= mid) ? 1u : 0u;
      red[tid] = c;
      __syncthreads();
      for (int off = THREADS / 2; off > 0; off >>= 1) {
        if (tid < off) red[tid] += red[tid + off];
        __syncthreads();
      }
      uint32_t totc = red[0];
      __syncthreads();
      if (totc >= KTOP) lo = mid; else hi = mid - 1;
    }
    uint32_t T = lo;
    if (tid == 0) s_cnt = 0;
    __syncthreads();
    for (int i = tid; i < NELEM; i += THREADS) {
      float x = src[i];
      if (fkey(x) > T) {
        uint32_t slot = atomicAdd(&s_cnt, 1u);    // LDS atomic, < KTOP hits
        s[slot] = composite(x, (uint32_t)i);
      }
    }
    __syncthreads();
    if (tid == 0) {
      uint32_t nGT = s_cnt, got = 0;
      for (int i = 0; i < NELEM && nGT + got < KTOP; ++i) {
        float x = src[i];
        if (fkey(x) == T) { s[nGT + got] = composite(x, (uint32_t)i); got++; }
      }
      s_cnt = KTOP;
    }
    __syncthreads();
    cnt = s_cnt;
  }

  uint32_t n = 256;
  while (n < cnt) n <<= 1;
  for (uint32_t i = cnt + tid; i < n; i += THREADS) s[i] = 0ull;
  __syncthreads();

  // bitonic sort, descending (n=256 typical: 36 single-iteration passes)
  for (uint32_t k = 2; k <= n; k <<= 1) {
    for (uint32_t j = k >> 1; j > 0; j >>= 1) {
      for (uint32_t i = tid; i < n; i += THREADS) {
        uint32_t ixj = i ^ j;
        if (ixj > i) {
          uint64_t a = s[i], c = s[ixj];
          bool desc = ((i & k) == 0);
          if (desc ? (a < c) : (a > c)) { s[i] = c; s[ixj] = a; }
        }
      }
      __syncthreads();
    }
  }

  // threshold-decay mask logic (scalar, replicated per thread)
  float smax = __uint_as_float((uint32_t)(s[0] >> 32));
  int mode;       // 0: score > thr ; 1: score >= thr ; 2: all true
  float thr = 0.1f;
  if (smax > 0.1f) {
    mode = 0;
  } else {
    float tmp = 0.1f;
    mode = 2;
    while (true) {
      tmp *= 0.9f;
      if (tmp < 0.01f) { mode = 2; break; }
      if (smax >= tmp) { mode = 1; thr = tmp; break; }
    }
  }
  if (tid < KTOP) {
    uint64_t comp = s[tid];
    float score = __uint_as_float((uint32_t)(comp >> 32));
    uint32_t idx = 0xFFFFFFFFu - (uint32_t)(comp & 0xFFFFFFFFu);
    uint32_t label = idx % NCLS;
    uint32_t bidx = idx / NCLS;
    if (bidx >= NQ) bidx = 0;  // safety
    float4 bb = ((const float4*)(bbox + (size_t)b * NQ * 4))[bidx];
    float hx = __fmul_rn(bb.z, 0.5f);
    float hy = __fmul_rn(bb.w, 0.5f);
    float x1 = __fadd_rn(__fmul_rn(__fsub_rn(bb.x, hx), 30.0f), -15.0f);
    float y1 = __fadd_rn(__fmul_rn(__fsub_rn(bb.y, hy), 60.0f), -30.0f);
    float x2 = __fadd_rn(__fmul_rn(__fadd_rn(bb.x, hx), 30.0f), -15.0f);
    float y2 = __fadd_rn(__fmul_rn(__fadd_rn(bb.y, hy), 60.0f), -30.0f);
    bool rmask = (x1 >= -20.0f) & (y1 >= -35.0f) & (x2 >= -20.0f) & (y2 >= -35.0f) &
                 (x1 <= 20.0f) & (y1 <= 35.0f) & (x2 <= 20.0f) & (y2 <= 35.0f);
    bool tmask = (mode == 2) || (mode == 0 ? (score > thr) : (score >= thr));
    bool mask = rmask && tmask;

    float* oBoxes  = out;                        // [B][K][4]
    float* oScores = out + B * KTOP * 4;         // [B][K]
    float* oLabels = oScores + B * KTOP;         // [B][K]
    float* oPts    = oLabels + B * KTOP;         // [B][K][NPTS][2]
    float* oMask   = oPts + B * KTOP * NPTS * 2; // [B][K]
    size_t rb = (size_t)b * KTOP + (size_t)tid;

    ((float4*)oBoxes)[rb] = mask ? make_float4(x1, y1, x2, y2)
                                 : make_float4(0.f, 0.f, 0.f, 0.f);
    oScores[rb] = mask ? score : 0.0f;
    oLabels[rb] = mask ? (float)label : 0.0f;
    oMask[rb]   = mask ? 1.0f : 0.0f;

    // pts row = 40 floats = 160 B, 16 B-aligned -> 10x float4
    const float4* ps = (const float4*)(pts + (size_t)b * NQ * NPTS * 2 + (size_t)bidx * NPTS * 2);
    float4* po = (float4*)(oPts + rb * NPTS * 2);
#pragma unroll
    for (int j = 0; j < 10; ++j) {
      float4 p = ps[j];
      float4 o;
      o.x = __fadd_rn(__fmul_rn(p.x, 30.0f), -15.0f);
      o.y = __fadd_rn(__fmul_rn(p.y, 60.0f), -30.0f);
      o.z = __fadd_rn(__fmul_rn(p.z, 30.0f), -15.0f);
      o.w = __fadd_rn(__fmul_rn(p.w, 60.0f), -30.0f);
      po[j] = mask ? o : make_float4(0.f, 0.f, 0.f, 0.f);
    }
  }
}

extern "C" void kernel_launch(void* const* d_in, const int* in_sizes, int n_in,
                              void* d_out, int out_size, void* d_ws, size_t ws_size,
                              hipStream_t stream) {
  const float* cls  = (const float*)d_in[0];
  const float* bbox = (const float*)d_in[1];
  const float* pts  = (const float*)d_in[2];
  float* out = (float*)d_out;

  uint8_t* ws = (uint8_t*)d_ws;
  uint32_t* counts = (uint32_t*)ws;                         // B*CBLOCKS u32 = 4 KiB
  uint32_t* done   = (uint32_t*)(ws + B * CBLOCKS * 4);     // B u32
  uint64_t* cand   = (uint64_t*)(ws + B * CBLOCKS * 4 + 256); // B*CBLOCKS*REG u64 = 512 KiB

  hipMemsetAsync(done, 0, B * sizeof(uint32_t), stream);
  fused_kernel<<<B * CBLOCKS, THREADS, 0, stream>>>(cls, bbox, pts, counts, cand, done, out);
}

// Round 6
// 184.505 us; speedup vs baseline: 1.7129x; 1.7129x over previous
//
#include <hip/hip_runtime.h>
#include <stdint.h>

#define B 8
#define NQ 100000
#define NCLS 10
#define NELEM 1000000        // elements per batch (NQ*NCLS)
#define NV4 250000           // float4 per batch
#define KTOP 100
#define NPTS 20
#define CAP 1024             // max candidates kept per batch (Poisson(159) >1024: ~0)
#define THREADS 256
#define CBLOCKS 128          // collect blocks per batch
#define REG 64               // candidate slots per block region (exp ~1.25 cands/block)
#define T0 3.6f              // prefilter: count>3.6 ~ Poisson(159); P(<100)~1e-6; fallback exact

// Order-preserving monotone key for f32 (larger float <-> larger key)
__device__ __forceinline__ uint32_t fkey(float x) {
  uint32_t u = __float_as_uint(x);
  return (u & 0x80000000u) ? ~u : (u | 0x80000000u);
}

__device__ __forceinline__ uint64_t composite(float logit, uint32_t idx) {
  float s = 1.0f / (1.0f + expf(-logit));
  // sorts desc by sigmoid f32 bits, then asc by index (matches top_k tie rule)
  return ((uint64_t)__float_as_uint(s) << 32) | (uint64_t)(0xFFFFFFFFu - idx);
}

// Per-block private regions: NO global atomics, NO device fences.
// (R2: same-address atomic-with-return = 124us; R5: __threadfence handoff = 110us.)
__global__ void collect_kernel(const float* __restrict__ cls,
                               uint32_t* __restrict__ counts,   // [B*CBLOCKS]
                               uint64_t* __restrict__ cand) {   // [B*CBLOCKS][REG]
  __shared__ uint32_t lcnt;
  int b   = blockIdx.x / CBLOCKS;
  int sub = blockIdx.x % CBLOCKS;
  if (threadIdx.x == 0) lcnt = 0;
  __syncthreads();
  const float4* src = (const float4*)(cls + (size_t)b * NELEM);
  const int STRIDE = CBLOCKS * THREADS;            // 32768 float4s
  int base = sub * THREADS + threadIdx.x;
  // 8 strided loads up-front for memory-level parallelism
  float4 v[8];
  int   idx[8];
#pragma unroll
  for (int k = 0; k < 8; ++k) {
    idx[k] = base + k * STRIDE;
    v[k] = (idx[k] < NV4) ? src[idx[k]] : make_float4(-100.f, -100.f, -100.f, -100.f);
  }
  uint64_t* region = cand + (size_t)(b * CBLOCKS + sub) * REG;
#pragma unroll
  for (int k = 0; k < 8; ++k) {
    float xs[4] = {v[k].x, v[k].y, v[k].z, v[k].w};
#pragma unroll
    for (int l = 0; l < 4; ++l) {
      if (xs[l] > T0) {
        uint32_t slot = atomicAdd(&lcnt, 1u);      // LDS atomic, ~1-2 hits/block
        if (slot < REG)
          region[slot] = composite(xs[l], (uint32_t)(4 * idx[k] + l));
      }
    }
  }
  __syncthreads();
  if (threadIdx.x == 0) counts[b * CBLOCKS + sub] = lcnt;  // raw (>REG -> fallback)
}

__global__ void final_kernel(const float* __restrict__ cls,
                             const float* __restrict__ bbox,
                             const float* __restrict__ pts,
                             const uint32_t* __restrict__ counts,
                             const uint64_t* __restrict__ cand,
                             float* __restrict__ out) {
  __shared__ uint64_t s[CAP];
  __shared__ uint64_t s2[KTOP];          // top-KTOP, sorted by rank-scatter
  __shared__ uint32_t sc[CBLOCKS];
  __shared__ uint32_t red[THREADS];
  __shared__ uint32_t s_bad, s_cnt;
  int b = blockIdx.x;
  int tid = threadIdx.x;

  if (tid == 0) s_bad = 0;
  __syncthreads();

  // parallel load + clamp of per-region counts
  uint32_t myc = 0;
  if (tid < CBLOCKS) {
    myc = counts[b * CBLOCKS + tid];
    if (myc > REG) { s_bad = 1; myc = REG; }
    sc[tid] = myc;
  }
  // Hillis-Steele inclusive scan over CBLOCKS entries
  for (int step = 1; step < CBLOCKS; step <<= 1) {
    __syncthreads();
    uint32_t add = (tid < CBLOCKS && tid >= step) ? sc[tid - step] : 0;
    __syncthreads();
    if (tid < CBLOCKS) sc[tid] += add;
  }
  __syncthreads();
  uint32_t total = sc[CBLOCKS - 1];
  uint32_t bad = s_bad || (total < KTOP) || (total > CAP);
  __syncthreads();

  uint32_t cnt;
  if (!bad) {
    // one region per thread (~1.25 elems each), latency-overlapped
    if (tid < CBLOCKS) {
      uint32_t off = sc[tid] - myc;
      const uint64_t* region = cand + (size_t)(b * CBLOCKS + tid) * REG;
      for (uint32_t j = 0; j < myc; ++j) s[off + j] = region[j];
    }
    cnt = total;
  } else {
    // exact fallback: binary-search the KTOP threshold over the raw logits.
    const float* src = cls + (size_t)b * NELEM;
    uint32_t lo = 0, hi = 0xFFFFFFFFu;
    while (lo < hi) {
      uint32_t mid = lo + ((hi - lo + 1) >> 1);
      uint32_t c = 0;
      for (int i = tid; i < NELEM; i += THREADS)
        c += (fkey(src[i]) >= mid) ? 1u : 0u;
      red[tid] = c;
      __syncthreads();
      for (int off = THREADS / 2; off > 0; off >>= 1) {
        if (tid < off) red[tid] += red[tid + off];
        __syncthreads();
      }
      uint32_t totc = red[0];
      __syncthreads();
      if (totc >= KTOP) lo = mid; else hi = mid - 1;
    }
    uint32_t T = lo;
    if (tid == 0) s_cnt = 0;
    __syncthreads();
    for (int i = tid; i < NELEM; i += THREADS) {
      float x = src[i];
      if (fkey(x) > T) {
        uint32_t slot = atomicAdd(&s_cnt, 1u);    // LDS atomic, < KTOP hits
        s[slot] = composite(x, (uint32_t)i);
      }
    }
    __syncthreads();
    if (tid == 0) {
      uint32_t nGT = s_cnt, got = 0;
      for (int i = 0; i < NELEM && nGT + got < KTOP; ++i) {
        float x = src[i];
        if (fkey(x) == T) { s[nGT + got] = composite(x, (uint32_t)i); got++; }
      }
      s_cnt = KTOP;
    }
    __syncthreads();
    cnt = s_cnt;
  }
  __syncthreads();

  // rank-selection: composites are unique, rank = #larger; one barrier total.
  // cnt~160: each thread scans cnt broadcast LDS reads (~1 elem/thread).
  for (uint32_t i = tid; i < cnt; i += THREADS) {
    uint64_t me = s[i];
    uint32_t r = 0;
    for (uint32_t j = 0; j < cnt; ++j) r += (s[j] > me) ? 1u : 0u;
    if (r < KTOP) s2[r] = me;
  }
  __syncthreads();

  // threshold-decay mask logic (scalar, replicated per thread)
  float smax = __uint_as_float((uint32_t)(s2[0] >> 32));
  int mode;       // 0: score > thr ; 1: score >= thr ; 2: all true
  float thr = 0.1f;
  if (smax > 0.1f) {
    mode = 0;
  } else {
    float tmp = 0.1f;
    mode = 2;
    while (true) {
      tmp *= 0.9f;
      if (tmp < 0.01f) { mode = 2; break; }
      if (smax >= tmp) { mode = 1; thr = tmp; break; }
    }
  }
  if (tid < KTOP) {
    uint64_t comp = s2[tid];
    float score = __uint_as_float((uint32_t)(comp >> 32));
    uint32_t idx = 0xFFFFFFFFu - (uint32_t)(comp & 0xFFFFFFFFu);
    uint32_t label = idx % NCLS;
    uint32_t bidx = idx / NCLS;
    if (bidx >= NQ) bidx = 0;  // safety
    float4 bb = ((const float4*)(bbox + (size_t)b * NQ * 4))[bidx];
    float hx = __fmul_rn(bb.z, 0.5f);
    float hy = __fmul_rn(bb.w, 0.5f);
    float x1 = __fadd_rn(__fmul_rn(__fsub_rn(bb.x, hx), 30.0f), -15.0f);
    float y1 = __fadd_rn(__fmul_rn(__fsub_rn(bb.y, hy), 60.0f), -30.0f);
    float x2 = __fadd_rn(__fmul_rn(__fadd_rn(bb.x, hx), 30.0f), -15.0f);
    float y2 = __fadd_rn(__fmul_rn(__fadd_rn(bb.y, hy), 60.0f), -30.0f);
    bool rmask = (x1 >= -20.0f) & (y1 >= -35.0f) & (x2 >= -20.0f) & (y2 >= -35.0f) &
                 (x1 <= 20.0f) & (y1 <= 35.0f) & (x2 <= 20.0f) & (y2 <= 35.0f);
    bool tmask = (mode == 2) || (mode == 0 ? (score > thr) : (score >= thr));
    bool mask = rmask && tmask;

    float* oBoxes  = out;                        // [B][K][4]
    float* oScores = out + B * KTOP * 4;         // [B][K]
    float* oLabels = oScores + B * KTOP;         // [B][K]
    float* oPts    = oLabels + B * KTOP;         // [B][K][NPTS][2]
    float* oMask   = oPts + B * KTOP * NPTS * 2; // [B][K]
    size_t rb = (size_t)b * KTOP + (size_t)tid;

    ((float4*)oBoxes)[rb] = mask ? make_float4(x1, y1, x2, y2)
                                 : make_float4(0.f, 0.f, 0.f, 0.f);
    oScores[rb] = mask ? score : 0.0f;
    oLabels[rb] = mask ? (float)label : 0.0f;
    oMask[rb]   = mask ? 1.0f : 0.0f;

    // pts row = 40 floats = 160 B, 16 B-aligned -> 10x float4
    const float4* ps = (const float4*)(pts + (size_t)b * NQ * NPTS * 2 + (size_t)bidx * NPTS * 2);
    float4* po = (float4*)(oPts + rb * NPTS * 2);
#pragma unroll
    for (int j = 0; j < 10; ++j) {
      float4 p = ps[j];
      float4 o;
      o.x = __fadd_rn(__fmul_rn(p.x, 30.0f), -15.0f);
      o.y = __fadd_rn(__fmul_rn(p.y, 60.0f), -30.0f);
      o.z = __fadd_rn(__fmul_rn(p.z, 30.0f), -15.0f);
      o.w = __fadd_rn(__fmul_rn(p.w, 60.0f), -30.0f);
      po[j] = mask ? o : make_float4(0.f, 0.f, 0.f, 0.f);
    }
  }
}

extern "C" void kernel_launch(void* const* d_in, const int* in_sizes, int n_in,
                              void* d_out, int out_size, void* d_ws, size_t ws_size,
                              hipStream_t stream) {
  const float* cls  = (const float*)d_in[0];
  const float* bbox = (const float*)d_in[1];
  const float* pts  = (const float*)d_in[2];
  float* out = (float*)d_out;

  uint8_t* ws = (uint8_t*)d_ws;
  uint32_t* counts = (uint32_t*)ws;                        // B*CBLOCKS u32 = 4 KiB
  uint64_t* cand   = (uint64_t*)(ws + B * CBLOCKS * 4);    // B*CBLOCKS*REG u64 = 512 KiB

  collect_kernel<<<B * CBLOCKS, THREADS, 0, stream>>>(cls, counts, cand);
  final_kernel<<<B, THREADS, 0, stream>>>(cls, bbox, pts, counts, cand, out);
}